// Round 7
// baseline (187.114 us; speedup 1.0000x reference)
//
#include <hip/hip_runtime.h>
#include <hip/hip_bf16.h>

typedef __bf16 bf16x8 __attribute__((ext_vector_type(8)));
typedef float floatx4 __attribute__((ext_vector_type(4)));
typedef unsigned uintx4 __attribute__((ext_vector_type(4)));

#define BATCH 256
#define INDIM 512
#define ODIM 10
#define HTOT 18432
#define NMODEL 128
#define NJPH (HTOT / 16)     // 1152 16-neuron groups (partial granularity)

__device__ __forceinline__ unsigned cvt2(float a, float b) {
    __hip_bfloat162 t = __float22bfloat162_rn(float2{a, b});   // RNE, packed
    return *(unsigned*)&t;
}

__device__ __forceinline__ bf16x8 ldfrag(const float* __restrict__ p) {
    floatx4 v0 = *(const floatx4*)p;
    floatx4 v1 = *(const floatx4*)(p + 4);
    uintx4 u;
    u.x = cvt2(v0[0], v0[1]); u.y = cvt2(v0[2], v0[3]);
    u.z = cvt2(v1[0], v1[1]); u.w = cvt2(v1[2], v1[3]);
    return *(bf16x8*)&u;
}

__device__ __forceinline__ float apply_act(float h, int aidx) {
    if (aidx == 0) return fmaxf(h, 0.f);
    if (aidx == 1) return 1.f - 2.f / (1.f + __expf(2.f * h));   // tanh, no-overflow form
    if (aidx == 2) return 1.f / (1.f + __expf(-h));              // sigmoid
    return h;                                                     // identity
}

// GEMM + act + out_w dot, NO LDS, NO barriers. grid = 288 j-tiles x 4 b-tiles
// = 1152 blocks x 256 thr (18 waves/CU). XCD swizzle: bid&7 = XCD slot; the 4
// b-blocks of a j-tile land on one XCD -> w row fetched from HBM once, L2 after.
// Wave wv owns j-range [j0+wv*16, +16) x all 64 b: acc[4] (16x16x32 MFMA).
// Fragment layout (verified R1-R6 via identical LDS indexing):
//   A[m=lane&15][k=(lane>>4)*8+i],  B[n=lane&15][k=(lane>>4)*8+i].
__global__ __launch_bounds__(256, 4) void gemm_kernel(
    const float* __restrict__ x, const float* __restrict__ hw,
    const float* __restrict__ hb, const float* __restrict__ ow,
    float* __restrict__ part)
{
    const int bid = blockIdx.x;
    const int xcd = bid & 7;
    const int k8  = bid >> 3;            // 0..143
    const int jt  = k8 >> 2;             // 0..35 (36 j-tiles per XCD slot)
    const int bb  = k8 & 3;
    const int j0  = (xcd * 36 + jt) * 64;
    const int b0  = bb * 64;
    const int lane = threadIdx.x & 63, wv = threadIdx.x >> 6;
    const int r = lane & 15, g = lane >> 4;

    const int jw = j0 + wv * 16;         // this wave's 16-j group
    const float* wrow = hw + (size_t)(jw + r) * INDIM + g * 8;
    const float* xrow = x  + (size_t)(b0 + r) * INDIM + g * 8;

    floatx4 acc[4];
    #pragma unroll
    for (int bt = 0; bt < 4; bt++) acc[bt] = (floatx4)0.f;

    for (int kk = 0; kk < INDIM; kk += 32) {
        bf16x8 af = ldfrag(wrow + kk);
        #pragma unroll
        for (int bt = 0; bt < 4; bt++) {
            bf16x8 bfr = ldfrag(xrow + (size_t)bt * 16 * INDIM + kk);
            acc[bt] = __builtin_amdgcn_mfma_f32_16x16x32_bf16(af, bfr, acc[bt], 0, 0, 0);
        }
    }

    // Epilogue. D layout: col(b)=lane&15, row(j in 16)=g*4+reg.
    const int aidx = jw / 4608;                       // wave-uniform (16 | 4608)
    const floatx4 bias = *(const floatx4*)&hb[jw + g * 4];
    #pragma unroll
    for (int bt = 0; bt < 4; bt++)
        #pragma unroll
        for (int q = 0; q < 4; q++)
            acc[bt][q] = apply_act(acc[bt][q] + bias[q], aidx);

    const int jph = jw >> 4;
    #pragma unroll
    for (int o = 0; o < ODIM; o++) {
        const floatx4 w4 = *(const floatx4*)&ow[(size_t)o * HTOT + jw + g * 4];
        #pragma unroll
        for (int bt = 0; bt < 4; bt++) {
            float p = acc[bt][0] * w4[0] + acc[bt][1] * w4[1]
                    + acc[bt][2] * w4[2] + acc[bt][3] * w4[3];
            p += __shfl_xor(p, 16, 64);
            p += __shfl_xor(p, 32, 64);
            if (lane < 16)
                part[((size_t)jph * ODIM + o) * BATCH + b0 + bt * 16 + r] = p;
        }
    }
}

// One block per (model, o): 1280 blocks x 256 threads (thread = b).
// Sums the model's 2..16 16-j partials + out_b, writes out[b][m][o] once.
__global__ __launch_bounds__(256) void finalize_kernel(
    const float* __restrict__ part, const float* __restrict__ out_b,
    float* __restrict__ out)
{
    const int mo = blockIdx.x;           // m*ODIM + o
    const int m = mo / ODIM, o = mo - m * ODIM;
    const int b = threadIdx.x;
    const int rep = m >> 3, idx = m & 7; // model m -> 32*(idx+1) neurons
    const int jp0 = 2 * (rep * 36 + (idx * (idx + 1)) / 2);
    const int cnt = 2 * (idx + 1);

    float s = out_b[mo];
    for (int c = 0; c < cnt; c++)
        s += part[((size_t)(jp0 + c) * ODIM + o) * BATCH + b];
    out[((size_t)b * NMODEL + m) * ODIM + o] = s;
}

extern "C" void kernel_launch(void* const* d_in, const int* in_sizes, int n_in,
                              void* d_out, int out_size, void* d_ws, size_t ws_size,
                              hipStream_t stream) {
    const float* x   = (const float*)d_in[0];
    const float* hw  = (const float*)d_in[1];
    const float* hb  = (const float*)d_in[2];
    const float* ow  = (const float*)d_in[3];
    const float* ob  = (const float*)d_in[4];
    float* out = (float*)d_out;
    float* part = (float*)d_ws;          // NJPH*ODIM*BATCH*4 = 11.8 MB

    gemm_kernel<<<(HTOT / 64) * (BATCH / 64), 256, 0, stream>>>(x, hw, hb, ow, part);
    finalize_kernel<<<NMODEL * ODIM, 256, 0, stream>>>(part, ob, out);
}

// Round 8
// 123.551 us; speedup vs baseline: 1.5145x; 1.5145x over previous
//
#include <hip/hip_runtime.h>
#include <hip/hip_bf16.h>

typedef __bf16 bf16x8 __attribute__((ext_vector_type(8)));
typedef float floatx4 __attribute__((ext_vector_type(4)));
typedef unsigned uintx4 __attribute__((ext_vector_type(4)));

#define BATCH 256
#define INDIM 512
#define ODIM 10
#define HTOT 18432
#define NMODEL 128
#define NJG (HTOT / 16)        // 1152 16-j groups
#define NKB (INDIM / 32)       // 16 k-blocks
#define NWTASK (NJG * NKB)     // 18432 w pack tasks
#define NXTASK (16 * NKB)      // 256 x pack tasks (16 bgroups)

__device__ __forceinline__ unsigned cvt2(float a, float b) {
    __hip_bfloat162 t = __float22bfloat162_rn(float2{a, b});   // RNE, packed
    return *(unsigned*)&t;
}

__device__ __forceinline__ float apply_act(float h, int aidx) {
    if (aidx == 0) return fmaxf(h, 0.f);
    if (aidx == 1) return 1.f - 2.f / (1.f + __expf(2.f * h));   // tanh, no-overflow form
    if (aidx == 2) return 1.f / (1.f + __expf(-h));              // sigmoid
    return h;                                                     // identity
}

// Pack w and x into MFMA A/B fragment order, fp32 -> bf16 (RNE).
// One WAVE per task (jg, kb): lane L holds frag elems
//   src[jg*16 + (L&15)][kb*32 + (L>>4)*8 + i], i=0..7
// stored contiguously at dst[(task*64 + L)*8] -> GEMM reads 1KB coalesced.
// grid = (NWTASK+NXTASK)/4 = 4672 blocks x 256 thr.
__global__ __launch_bounds__(256) void pack_kernel(
    const float* __restrict__ hw, const float* __restrict__ x,
    unsigned short* __restrict__ wpk, unsigned short* __restrict__ xpk)
{
    const int lane = threadIdx.x & 63, wv = threadIdx.x >> 6;
    const int task = blockIdx.x * 4 + wv;
    const int r = lane & 15, g = lane >> 4;

    const float* src;
    unsigned short* dst;
    int t2;
    if (task < NWTASK) {
        // task = jg*16 + kb
        src = hw + (size_t)((task >> 4) * 16 + r) * INDIM + (task & 15) * 32 + g * 8;
        dst = wpk + ((size_t)task * 64 + lane) * 8;
    } else {
        t2 = task - NWTASK;     // = bg*16 + kb
        src = x + (size_t)((t2 >> 4) * 16 + r) * INDIM + (t2 & 15) * 32 + g * 8;
        dst = xpk + ((size_t)t2 * 64 + lane) * 8;
    }
    floatx4 v0 = *(const floatx4*)src;
    floatx4 v1 = *(const floatx4*)(src + 4);
    uintx4 u;
    u.x = cvt2(v0[0], v0[1]); u.y = cvt2(v0[2], v0[3]);
    u.z = cvt2(v1[0], v1[1]); u.w = cvt2(v1[2], v1[3]);
    *(uintx4*)dst = u;
}

// GEMM + act + out_w dot. NO LDS, NO barriers, every load a coalesced 1KB
// dwordx4. grid = 288 j-tiles x 4 b-tiles = 1152 x 256 thr. XCD swizzle:
// the 4 b-blocks of a j-tile share one XCD -> wpk re-reads hit that L2.
// Wave wv: jg = j-tile*4+wv, all 64 b via acc[4] (16x16x32 bf16 MFMA).
__global__ __launch_bounds__(256, 5) void gemm_kernel(
    const unsigned short* __restrict__ wpk, const unsigned short* __restrict__ xpk,
    const float* __restrict__ hb, const float* __restrict__ ow,
    float* __restrict__ part)
{
    const int bid = blockIdx.x;
    const int xcd = bid & 7;
    const int k8  = bid >> 3;            // 0..143
    const int jt  = k8 >> 2;             // 0..35
    const int bb  = k8 & 3;
    const int jtile = xcd * 36 + jt;     // 0..287
    const int b0  = bb * 64;
    const int lane = threadIdx.x & 63, wv = threadIdx.x >> 6;
    const int r = lane & 15, g = lane >> 4;

    const int jg = jtile * 4 + wv;       // this wave's 16-j group
    const unsigned short* wbase = wpk + ((size_t)jg * 16 * 64 + lane) * 8;
    const unsigned short* xbase = xpk + ((size_t)bb * 4 * 16 * 64 + lane) * 8;

    floatx4 acc[4];
    #pragma unroll
    for (int bt = 0; bt < 4; bt++) acc[bt] = (floatx4)0.f;

    #pragma unroll
    for (int kb = 0; kb < NKB; kb++) {
        bf16x8 af = *(const bf16x8*)(wbase + (size_t)kb * 64 * 8);
        #pragma unroll
        for (int bt = 0; bt < 4; bt++) {
            bf16x8 bfr = *(const bf16x8*)(xbase + ((size_t)bt * 16 + kb) * 64 * 8);
            acc[bt] = __builtin_amdgcn_mfma_f32_16x16x32_bf16(af, bfr, acc[bt], 0, 0, 0);
        }
    }

    // Epilogue. D layout: col(b)=lane&15, row(j in 16)=g*4+reg (verified R1-R7).
    const int jw = jg * 16;
    const int aidx = jw / 4608;                       // wave-uniform
    const floatx4 bias = *(const floatx4*)&hb[jw + g * 4];
    #pragma unroll
    for (int bt = 0; bt < 4; bt++)
        #pragma unroll
        for (int q = 0; q < 4; q++)
            acc[bt][q] = apply_act(acc[bt][q] + bias[q], aidx);

    #pragma unroll
    for (int o = 0; o < ODIM; o++) {
        const floatx4 w4 = *(const floatx4*)&ow[(size_t)o * HTOT + jw + g * 4];
        #pragma unroll
        for (int bt = 0; bt < 4; bt++) {
            float p = acc[bt][0] * w4[0] + acc[bt][1] * w4[1]
                    + acc[bt][2] * w4[2] + acc[bt][3] * w4[3];
            p += __shfl_xor(p, 16, 64);
            p += __shfl_xor(p, 32, 64);
            if (lane < 16)
                part[((size_t)jg * ODIM + o) * BATCH + b0 + bt * 16 + r] = p;
        }
    }
}

// One block per (model, o): 1280 blocks x 256 threads (thread = b).
__global__ __launch_bounds__(256) void finalize_kernel(
    const float* __restrict__ part, const float* __restrict__ out_b,
    float* __restrict__ out)
{
    const int mo = blockIdx.x;           // m*ODIM + o
    const int m = mo / ODIM, o = mo - m * ODIM;
    const int b = threadIdx.x;
    const int rep = m >> 3, idx = m & 7; // model m -> 32*(idx+1) neurons
    const int jp0 = 2 * (rep * 36 + (idx * (idx + 1)) / 2);
    const int cnt = 2 * (idx + 1);

    float s = out_b[mo];
    for (int c = 0; c < cnt; c++)
        s += part[((size_t)(jp0 + c) * ODIM + o) * BATCH + b];
    out[((size_t)b * NMODEL + m) * ODIM + o] = s;
}

extern "C" void kernel_launch(void* const* d_in, const int* in_sizes, int n_in,
                              void* d_out, int out_size, void* d_ws, size_t ws_size,
                              hipStream_t stream) {
    const float* x   = (const float*)d_in[0];
    const float* hw  = (const float*)d_in[1];
    const float* hb  = (const float*)d_in[2];
    const float* ow  = (const float*)d_in[3];
    const float* ob  = (const float*)d_in[4];
    float* out = (float*)d_out;

    unsigned short* wpk = (unsigned short*)d_ws;                 // 18.9 MB
    unsigned short* xpk = wpk + (size_t)NWTASK * 64 * 8;         // 256 KB
    float* part = (float*)(xpk + (size_t)NXTASK * 64 * 8);       // 11.8 MB

    pack_kernel<<<(NWTASK + NXTASK) / 4, 256, 0, stream>>>(hw, x, wpk, xpk);
    gemm_kernel<<<(HTOT / 64) * (BATCH / 64), 256, 0, stream>>>(wpk, xpk, hb, ow, part);
    finalize_kernel<<<NMODEL * ODIM, 256, 0, stream>>>(part, ob, out);
}